// Round 3
// baseline (317.780 us; speedup 1.0000x reference)
//
#include <hip/hip_runtime.h>
#include <math.h>

#define LAYERS 6
#define BATCH 128
#define NQ 2000
#define NC 3
#define NP 20
#define TOPK 100
#define QC (NQ * NC) /* 6000 */
#define NTHREADS 256
#define MAXPER 24          /* ceil(6000/256) */
#define REM 112            /* 6000 - 23*256: threads < REM hold 24 keys */
#define TIE_CAP 256

// Output layout (float32, flat in reference return order):
//   boxes[128,100,4] @0 | scores[128,100] @51200 | labels @64000 |
//   pts[128,100,20,2] @76800 | mask @588800
#define BOXES_OFF 0
#define SCORES_OFF 51200
#define LABELS_OFF 64000
#define PTS_OFF 76800
#define MASK_OFF 588800

// One radix-select refinement pass over NBITS bits at SHIFT.
// 5 barriers; scan is register/shuffle-based (no Hillis-Steele).
template <int SHIFT, int NBITS>
__device__ inline void radix_pass(const unsigned int* __restrict__ rv, int cnt,
                                  unsigned int& prefix, unsigned int& pmask, int& need,
                                  int* hist, int* scanb, int* wtot,
                                  int* sBin, int* sGt,
                                  int tid, int lane, int wid)
{
    constexpr int NB = 1 << NBITS;
    constexpr unsigned int DMASK = (unsigned int)(NB - 1);
    constexpr int BP = NB / NTHREADS;   // bins per thread (8 or 4)

    #pragma unroll
    for (int j = 0; j < BP; ++j) hist[tid * BP + j] = 0;
    __syncthreads();

    for (int k = 0; k < cnt; ++k) {
        const unsigned int u = rv[k];
        if ((u & pmask) == prefix) atomicAdd(&hist[(u >> SHIFT) & DMASK], 1);
    }
    __syncthreads();

    // Thread-local suffix sums over its BP consecutive bins.
    int v[BP];
    int tot = 0;
    #pragma unroll
    for (int j = BP - 1; j >= 0; --j) { tot += hist[tid * BP + j]; v[j] = tot; }

    // Wave-level inclusive suffix scan of thread totals (Kogge-Stone, registers).
    int incl = tot;
    #pragma unroll
    for (int off = 1; off < 64; off <<= 1) {
        const int o = __shfl_down(incl, off);
        incl += (lane + off < 64) ? o : 0;
    }
    if (lane == 0) wtot[wid] = incl;   // whole-wave total
    __syncthreads();

    int higher = 0;
    for (int w = wid + 1; w < 4; ++w) higher += wtot[w];
    const int base = higher + (incl - tot);   // sum over threads strictly after me

    #pragma unroll
    for (int j = 0; j < BP; ++j) scanb[tid * BP + j] = base + v[j];
    __syncthreads();

    // Unique bin with scanb[bin] >= need > scanb[bin+1].
    #pragma unroll
    for (int j = 0; j < BP; ++j) {
        const int bin = tid * BP + j;
        const int s = base + v[j];
        const int nxt = (bin == NB - 1) ? 0 : scanb[bin + 1];
        if (s >= need && (bin == NB - 1 || nxt < need)) { *sBin = bin; *sGt = nxt; }
    }
    __syncthreads();

    prefix |= ((unsigned int)*sBin) << SHIFT;
    pmask |= DMASK << SHIFT;
    need -= *sGt;
}

__global__ __launch_bounds__(NTHREADS) void maptr_post_kernel(
    const float* __restrict__ cls,   // last layer [B,Q,C]
    const float* __restrict__ bbox,  // last layer [B,Q,4]
    const float* __restrict__ pts,   // last layer [B,Q,P,2]
    float* __restrict__ out)
{
    const int b = blockIdx.x;
    const int tid = threadIdx.x;
    const int lane = tid & 63;
    const int wid = tid >> 6;

    __shared__ int hist[2048];
    __shared__ int scanb[2048];
    __shared__ int wtot[4];
    __shared__ int sBin, sGt;
    __shared__ unsigned int cand_u[TOPK];
    __shared__ int cand_i[TOPK];
    __shared__ int tie_i[TIE_CAP];
    __shared__ int nCand, nTie;
    __shared__ float topv[TOPK];
    __shared__ int topi[TOPK];
    __shared__ int sbi[TOPK];
    __shared__ float smask[TOPK];

    if (tid == 0) { nCand = 0; nTie = 0; }

    // Keys in registers, order-preserving uint transform (sigmoid monotone).
    const float* clsb = cls + (size_t)b * QC;
    const int cnt = (tid < REM) ? MAXPER : (MAXPER - 1);
    unsigned int rv[MAXPER];
    for (int k = 0; k < cnt; ++k) {
        const unsigned int bits = __float_as_uint(clsb[tid + k * NTHREADS]);
        rv[k] = (bits & 0x80000000u) ? ~bits : (bits | 0x80000000u);
    }

    unsigned int prefix = 0, pmask = 0;
    int need = TOPK;
    radix_pass<21, 11>(rv, cnt, prefix, pmask, need, hist, scanb, wtot, &sBin, &sGt, tid, lane, wid);
    radix_pass<10, 11>(rv, cnt, prefix, pmask, need, hist, scanb, wtot, &sBin, &sGt, tid, lane, wid);
    radix_pass<0, 10>(rv, cnt, prefix, pmask, need, hist, scanb, wtot, &sBin, &sGt, tid, lane, wid);

    const unsigned int T32 = prefix;   // exact 100th-largest key
    const int R = need;                // ties at T32 admitted by smallest index

    // Collect strict-greaters (G < 100) and tie indices.
    for (int k = 0; k < cnt; ++k) {
        const unsigned int u = rv[k];
        const int i = tid + k * NTHREADS;
        if (u > T32) {
            const int p = atomicAdd(&nCand, 1);
            cand_u[p] = u; cand_i[p] = i;
        } else if (u == T32) {
            const int p = atomicAdd(&nTie, 1);
            if (p < TIE_CAP) tie_i[p] = i;
        }
    }
    __syncthreads();
    const int G = nCand;
    const int E = (nTie < TIE_CAP) ? nTie : TIE_CAP;
    if (tid < E) {
        const int mine = tie_i[tid];
        int rk = 0;
        for (int j = 0; j < E; ++j) rk += (tie_i[j] < mine);
        if (rk < R) { cand_u[G + rk] = T32; cand_i[G + rk] = mine; }
    }
    __syncthreads();

    // Rank the 100 selected: descending key, ascending index (top_k order).
    if (tid < TOPK) {
        const unsigned int u = cand_u[tid];
        const int ii = cand_i[tid];
        int rank = 0;
        for (int j = 0; j < TOPK; ++j) {
            const unsigned int uj = cand_u[j];
            const int ij = cand_i[j];
            rank += (uj > u) || (uj == u && ij < ii);
        }
        const unsigned int bits = (u & 0x80000000u) ? (u & 0x7fffffffu) : ~u;
        topv[rank] = __uint_as_float(bits);
        topi[rank] = ii;
    }
    __syncthreads();

    float* const boxes_out = out + BOXES_OFF;
    float* const scores_out = out + SCORES_OFF;
    float* const labels_out = out + LABELS_OFF;
    float* const pts_out = out + PTS_OFF;
    float* const mask_out = out + MASK_OFF;

    if (tid < TOPK) {
        const int m = tid;
        const int idx = topi[m];
        const float lv = topv[m];
        const float score = 1.0f / (1.0f + expf(-lv));
        const int bi = idx / 3;
        const int label = idx - bi * 3;

        const float4 bb = *(const float4*)(bbox + ((size_t)b * NQ + bi) * 4);
        const float bx1 = (bb.x - 0.5f * bb.z) * 30.0f - 15.0f;
        const float by1 = (bb.y - 0.5f * bb.w) * 60.0f - 30.0f;
        const float bx2 = (bb.x + 0.5f * bb.z) * 30.0f - 15.0f;
        const float by2 = (bb.y + 0.5f * bb.w) * 60.0f - 30.0f;

        const bool mk = (bx1 >= -20.0f) && (by1 >= -35.0f) && (bx2 >= -20.0f) && (by2 >= -35.0f) &&
                        (bx1 <= 20.0f) && (by1 <= 35.0f) && (bx2 <= 20.0f) && (by2 <= 35.0f);

        const size_t bm = (size_t)b * TOPK + m;
        boxes_out[bm * 4 + 0] = mk ? bx1 : 0.0f;
        boxes_out[bm * 4 + 1] = mk ? by1 : 0.0f;
        boxes_out[bm * 4 + 2] = mk ? bx2 : 0.0f;
        boxes_out[bm * 4 + 3] = mk ? by2 : 0.0f;
        scores_out[bm] = mk ? score : 0.0f;
        labels_out[bm] = mk ? (float)label : -1.0f;
        mask_out[bm] = mk ? 1.0f : 0.0f;
        sbi[m] = bi;
        smask[m] = mk ? 1.0f : 0.0f;
    }
    __syncthreads();

    // Points: 100*20 = 2000 (m,p) tasks.
    for (int t = tid; t < TOPK * NP; t += NTHREADS) {
        const int m = t / NP;
        const int p = t - m * NP;
        const int bi = sbi[m];
        const bool mk = smask[m] != 0.0f;
        const float2 pv = *(const float2*)(pts + (((size_t)b * NQ + bi) * NP + p) * 2);
        const size_t o = (((size_t)b * TOPK + m) * NP + p) * 2;
        pts_out[o + 0] = mk ? (pv.x * 30.0f - 15.0f) : 0.0f;
        pts_out[o + 1] = mk ? (pv.y * 60.0f - 30.0f) : 0.0f;
    }
}

extern "C" void kernel_launch(void* const* d_in, const int* in_sizes, int n_in,
                              void* d_out, int out_size, void* d_ws, size_t ws_size,
                              hipStream_t stream) {
    const float* cls = (const float*)d_in[0] + (size_t)(LAYERS - 1) * BATCH * NQ * NC;
    const float* bbox = (const float*)d_in[1] + (size_t)(LAYERS - 1) * BATCH * NQ * 4;
    const float* pts = (const float*)d_in[2] + (size_t)(LAYERS - 1) * BATCH * NQ * NP * 2;
    maptr_post_kernel<<<BATCH, NTHREADS, 0, stream>>>(cls, bbox, pts, (float*)d_out);
}

// Round 4
// 300.850 us; speedup vs baseline: 1.0563x; 1.0563x over previous
//
#include <hip/hip_runtime.h>
#include <math.h>

#define LAYERS 6
#define BATCH 128
#define NQ 2000
#define NC 3
#define NP 20
#define TOPK 100
#define QC 6000
#define NTHREADS 256
#define KPT 24            /* 24*256 = 6144 >= 6000, padded with key 0 */
#define NB 2048           /* top-11-bit histogram bins */
#define BP (NB / NTHREADS)/* 8 bins per thread */
#define CAP 2048          /* candidate capacity (C ~ 100-250 expected) */

// Output layout (float32, flat in reference return order):
//   boxes[128,100,4] @0 | scores[128,100] @51200 | labels @64000 |
//   pts[128,100,20,2] @76800 | mask @588800
#define BOXES_OFF 0
#define SCORES_OFF 51200
#define LABELS_OFF 64000
#define PTS_OFF 76800
#define MASK_OFF 588800

__global__ __launch_bounds__(NTHREADS) void maptr_post_kernel(
    const float* __restrict__ cls,   // last layer [B,Q,C]
    const float* __restrict__ bbox,  // last layer [B,Q,4]
    const float* __restrict__ pts,   // last layer [B,Q,P,2]
    float* __restrict__ out)
{
    const int b = blockIdx.x;
    const int tid = threadIdx.x;
    const int lane = tid & 63;
    const int wid = tid >> 6;

    __shared__ int hist[NB];
    __shared__ int scanb[NB];
    __shared__ int wtot[4];
    __shared__ int sBin;
    __shared__ unsigned int cand_u[CAP];
    __shared__ int cand_i[CAP];
    __shared__ int nCand;
    __shared__ float topv[TOPK];
    __shared__ int topi[TOPK];
    __shared__ int sbi[TOPK];
    __shared__ float smask[TOPK];

    #pragma unroll
    for (int j = 0; j < BP; ++j) hist[tid * BP + j] = 0;
    if (tid == 0) nCand = 0;

    // Keys in true VGPRs: compile-time-bounded, fully unrolled, no dynamic
    // indexing, no pointer escape. Pad slots get key 0 (= -NaN bit pattern,
    // strictly below every real float key).
    const float* clsb = cls + (size_t)b * QC;
    unsigned int rv[KPT];
    #pragma unroll
    for (int k = 0; k < KPT; ++k) {
        const int i = tid + k * NTHREADS;
        unsigned int key = 0u;
        if (i < QC) {
            const unsigned int bits = __float_as_uint(clsb[i]);
            key = (bits & 0x80000000u) ? ~bits : (bits | 0x80000000u);
        }
        rv[k] = key;
    }
    __syncthreads();

    // Single 11-bit histogram over key top bits. (Pads land in bin 0 —
    // harmless: the threshold bin for real data is far above 0.)
    #pragma unroll
    for (int k = 0; k < KPT; ++k) atomicAdd(&hist[rv[k] >> 21], 1);
    __syncthreads();

    // Suffix scan: scanb[bin] = count(topbits >= bin).
    int v[BP];
    int tot = 0;
    #pragma unroll
    for (int j = BP - 1; j >= 0; --j) { tot += hist[tid * BP + j]; v[j] = tot; }
    int incl = tot;
    #pragma unroll
    for (int off = 1; off < 64; off <<= 1) {
        const int o = __shfl_down(incl, off);
        incl += (lane + off < 64) ? o : 0;
    }
    if (lane == 0) wtot[wid] = incl;
    __syncthreads();
    int higher = 0;
    #pragma unroll
    for (int w = 0; w < 4; ++w) higher += (w > wid) ? wtot[w] : 0;
    const int base = higher + (incl - tot);
    #pragma unroll
    for (int j = 0; j < BP; ++j) scanb[tid * BP + j] = base + v[j];
    __syncthreads();

    // Threshold bin T: scanb[T] >= TOPK > scanb[T+1] (unique).
    #pragma unroll
    for (int j = 0; j < BP; ++j) {
        const int bin = tid * BP + j;
        const int s = base + v[j];
        const int nxt = (bin == NB - 1) ? 0 : scanb[bin + 1];
        if (s >= TOPK && (bin == NB - 1 || nxt < TOPK)) sBin = bin;
    }
    __syncthreads();
    const unsigned int T = (unsigned int)sBin;

    // Compact candidates (topbits >= T): C = scanb[T] in [100, ~250] here.
    #pragma unroll
    for (int k = 0; k < KPT; ++k) {
        if ((rv[k] >> 21) >= T) {
            const int p = atomicAdd(&nCand, 1);
            if (p < CAP) { cand_u[p] = rv[k]; cand_i[p] = tid + k * NTHREADS; }
        }
    }
    __syncthreads();
    const int C = (nCand < CAP) ? nCand : CAP;

    // Exact all-pairs rank: descending key, ascending index on ties
    // (matches lax.top_k stable order). Ranks are unique; keep rank < 100.
    for (int s = tid; s < C; s += NTHREADS) {
        const unsigned int u = cand_u[s];
        const int ii = cand_i[s];
        int rank = 0;
        for (int j = 0; j < C; ++j) {
            const unsigned int uj = cand_u[j];
            const int ij = cand_i[j];
            rank += (uj > u) || (uj == u && ij < ii);
        }
        if (rank < TOPK) {
            const unsigned int bits = (u & 0x80000000u) ? (u & 0x7fffffffu) : ~u;
            topv[rank] = __uint_as_float(bits);
            topi[rank] = ii;
        }
    }
    __syncthreads();

    float* const boxes_out = out + BOXES_OFF;
    float* const scores_out = out + SCORES_OFF;
    float* const labels_out = out + LABELS_OFF;
    float* const pts_out = out + PTS_OFF;
    float* const mask_out = out + MASK_OFF;

    if (tid < TOPK) {
        const int m = tid;
        const int idx = topi[m];
        const float lv = topv[m];
        const float score = 1.0f / (1.0f + expf(-lv));
        const int bi = idx / 3;
        const int label = idx - bi * 3;

        const float4 bb = *(const float4*)(bbox + ((size_t)b * NQ + bi) * 4);
        const float bx1 = (bb.x - 0.5f * bb.z) * 30.0f - 15.0f;
        const float by1 = (bb.y - 0.5f * bb.w) * 60.0f - 30.0f;
        const float bx2 = (bb.x + 0.5f * bb.z) * 30.0f - 15.0f;
        const float by2 = (bb.y + 0.5f * bb.w) * 60.0f - 30.0f;

        const bool mk = (bx1 >= -20.0f) && (by1 >= -35.0f) && (bx2 >= -20.0f) && (by2 >= -35.0f) &&
                        (bx1 <= 20.0f) && (by1 <= 35.0f) && (bx2 <= 20.0f) && (by2 <= 35.0f);

        const size_t bm = (size_t)b * TOPK + m;
        boxes_out[bm * 4 + 0] = mk ? bx1 : 0.0f;
        boxes_out[bm * 4 + 1] = mk ? by1 : 0.0f;
        boxes_out[bm * 4 + 2] = mk ? bx2 : 0.0f;
        boxes_out[bm * 4 + 3] = mk ? by2 : 0.0f;
        scores_out[bm] = mk ? score : 0.0f;
        labels_out[bm] = mk ? (float)label : -1.0f;
        mask_out[bm] = mk ? 1.0f : 0.0f;
        sbi[m] = bi;
        smask[m] = mk ? 1.0f : 0.0f;
    }
    __syncthreads();

    // Points: 100*20 = 2000 (m,p) tasks.
    for (int t = tid; t < TOPK * NP; t += NTHREADS) {
        const int m = t / NP;
        const int p = t - m * NP;
        const int bi = sbi[m];
        const bool mk = smask[m] != 0.0f;
        const float2 pv = *(const float2*)(pts + (((size_t)b * NQ + bi) * NP + p) * 2);
        const size_t o = (((size_t)b * TOPK + m) * NP + p) * 2;
        pts_out[o + 0] = mk ? (pv.x * 30.0f - 15.0f) : 0.0f;
        pts_out[o + 1] = mk ? (pv.y * 60.0f - 30.0f) : 0.0f;
    }
}

extern "C" void kernel_launch(void* const* d_in, const int* in_sizes, int n_in,
                              void* d_out, int out_size, void* d_ws, size_t ws_size,
                              hipStream_t stream) {
    const float* cls = (const float*)d_in[0] + (size_t)(LAYERS - 1) * BATCH * NQ * NC;
    const float* bbox = (const float*)d_in[1] + (size_t)(LAYERS - 1) * BATCH * NQ * 4;
    const float* pts = (const float*)d_in[2] + (size_t)(LAYERS - 1) * BATCH * NQ * NP * 2;
    maptr_post_kernel<<<BATCH, NTHREADS, 0, stream>>>(cls, bbox, pts, (float*)d_out);
}